// Round 5
// baseline (324.965 us; speedup 1.0000x reference)
//
#include <hip/hip_runtime.h>

#define LN_EPS 1e-5f

// Kernel 1: w_rowsum[p][c] = sum_k weights[p][c][k].  One wave per (p,c) row
// of 256 floats; float4 loads are fully coalesced (1 KB per wave).
__global__ __launch_bounds__(256) void wrowsum_kernel(
    const float* __restrict__ w, float* __restrict__ wr, int n_rows) {
  const int lane = threadIdx.x & 63;
  const int wv   = threadIdx.x >> 6;
  const int rc   = blockIdx.x * 4 + wv;          // p*C + c
  if (rc >= n_rows) return;
  const float4 v = reinterpret_cast<const float4*>(w)[(size_t)rc * 64 + lane];
  float s = v.x + v.y + v.z + v.w;
#pragma unroll
  for (int off = 32; off; off >>= 1) s += __shfl_xor(s, off);
  if (lane == 0) wr[rc] = s;
}

// Kernel 2: fused pointwise + LayerNorm + residual/ReLU + [C x 5] GEMV.
// One wave per (b,p) row; 4 channels per lane via float4; wave-only
// reductions (no LDS, no __syncthreads).
__global__ __launch_bounds__(256) void fused_main(
    const float* __restrict__ features,
    const float* __restrict__ wrow,
    const float* __restrict__ bias,
    const float* __restrict__ gamma,
    const float* __restrict__ beta,
    const float* __restrict__ lin_w,
    const float* __restrict__ lin_b,
    float* __restrict__ out,
    int n_rows, int P) {
  const int lane = threadIdx.x & 63;
  const int wv   = threadIdx.x >> 6;
  const int r    = blockIdx.x * 4 + wv;          // row id in [0, B*P)
  if (r >= n_rows) return;
  const int p = r % P;

  const float4 f  = reinterpret_cast<const float4*>(features)[(size_t)r * 64 + lane];
  const float4 wr = reinterpret_cast<const float4*>(wrow + (size_t)p * 256)[lane];
  const float4 bs = reinterpret_cast<const float4*>(bias + (size_t)p * 256)[lane];
  const float4 g  = reinterpret_cast<const float4*>(gamma)[lane];
  const float4 bt = reinterpret_cast<const float4*>(beta)[lane];

  // point_wise = f * w_rowsum + bias
  const float pw0 = fmaf(f.x, wr.x, bs.x);
  const float pw1 = fmaf(f.y, wr.y, bs.y);
  const float pw2 = fmaf(f.z, wr.z, bs.z);
  const float pw3 = fmaf(f.w, wr.w, bs.w);

  // wave reduction: sum and sum-of-squares
  float s1 = (pw0 + pw1) + (pw2 + pw3);
  float s2 = fmaf(pw0, pw0, fmaf(pw1, pw1, fmaf(pw2, pw2, pw3 * pw3)));
#pragma unroll
  for (int off = 32; off; off >>= 1) {
    s1 += __shfl_xor(s1, off);
    s2 += __shfl_xor(s2, off);
  }
  const float mu  = s1 * (1.0f / 256.0f);
  const float var = fmaf(-mu, mu, s2 * (1.0f / 256.0f));
  const float inv = rsqrtf(var + LN_EPS);

  // h = relu(f + ((pw - mu) * inv) * gamma + beta)
  const float h0 = fmaxf(fmaf((pw0 - mu) * inv, g.x, bt.x) + f.x, 0.0f);
  const float h1 = fmaxf(fmaf((pw1 - mu) * inv, g.y, bt.y) + f.y, 0.0f);
  const float h2 = fmaxf(fmaf((pw2 - mu) * inv, g.z, bt.z) + f.z, 0.0f);
  const float h3 = fmaxf(fmaf((pw3 - mu) * inv, g.w, bt.w) + f.w, 0.0f);

  // out[r][d] = sum_c h[c] * lin_w[d][c] + lin_b[d]
  float acc[5];
#pragma unroll
  for (int d = 0; d < 5; ++d) {
    const float4 lw = reinterpret_cast<const float4*>(lin_w + d * 256)[lane];
    acc[d] = fmaf(h0, lw.x, fmaf(h1, lw.y, fmaf(h2, lw.z, h3 * lw.w)));
  }
#pragma unroll
  for (int off = 32; off; off >>= 1) {
#pragma unroll
    for (int d = 0; d < 5; ++d) acc[d] += __shfl_xor(acc[d], off);
  }

  if (lane < 5) {
    float v;
    switch (lane) {
      case 0:  v = acc[0]; break;
      case 1:  v = acc[1]; break;
      case 2:  v = acc[2]; break;
      case 3:  v = acc[3]; break;
      default: v = acc[4]; break;
    }
    out[(size_t)r * 5 + lane] = v + lin_b[lane];
  }
}

extern "C" void kernel_launch(void* const* d_in, const int* in_sizes, int n_in,
                              void* d_out, int out_size, void* d_ws, size_t ws_size,
                              hipStream_t stream) {
  const float* features = (const float*)d_in[0];  // [B,P,C]
  const float* weights  = (const float*)d_in[1];  // [P,C,C]
  const float* bias     = (const float*)d_in[2];  // [P,C]
  const float* gamma    = (const float*)d_in[3];  // [C]
  const float* beta     = (const float*)d_in[4];  // [C]
  const float* lin_w    = (const float*)d_in[5];  // [D,C]
  const float* lin_b    = (const float*)d_in[6];  // [D]
  float* out = (float*)d_out;

  const int C  = 256;
  const int PC = in_sizes[2];          // P*C
  const int P  = PC / C;               // 25
  const int BP = in_sizes[0] / C;      // B*P rows = 204800

  float* wr = (float*)d_ws;            // [P*C] workspace

  // Kernel 1: row-sums of weights (6.55 MB read, ~1 us)
  wrowsum_kernel<<<(PC + 3) / 4, 256, 0, stream>>>(weights, wr, PC);

  // Kernel 2: fused main pass (one sweep over features)
  fused_main<<<(BP + 3) / 4, 256, 0, stream>>>(
      features, wr, bias, gamma, beta, lin_w, lin_b, out, BP, P);
}